// Round 7
// baseline (190890.430 us; speedup 1.0000x reference)
//
#include <hip/hip_runtime.h>
#include <hip/hip_bf16.h>
#include <stdint.h>

#define LSEQ 4096

// workspace float offsets
#define LLC_OFF   0        // 3 slots x 4096 floats (256 WGs x 16)      = 12288 f
#define LOC_OFF   12288    // 8 XCDs x 3 slots x 4096 floats            = 98304 f
#define CLAIM_OFF 110592   // 8 ints (relay election)
#define DTYPE_OFF 110600   // 1 int
#define SCALE_OFF 110656   // 4096 f

typedef float f32x4 __attribute__((ext_vector_type(4)));
typedef int   i32x4 __attribute__((ext_vector_type(4)));

// ---------- helpers ----------
__device__ __forceinline__ float bflo(unsigned int u){ return __uint_as_float(u << 16); }
__device__ __forceinline__ float bfhi(unsigned int u){ return __uint_as_float(u & 0xFFFF0000u); }

__device__ __forceinline__ float wred(float v){
#pragma unroll
  for (int m = 1; m < 64; m <<= 1) v += __shfl_xor(v, m, 64);
  return v;
}

__device__ __forceinline__ void keep4(float4 &v){
  asm volatile("" : "+v"(v.x), "+v"(v.y), "+v"(v.z), "+v"(v.w));
}

// sc0 sc1: LLC-coherent (bypass L1+L2)
__device__ __forceinline__ void st4_sc(float* p, f32x4 v){
  asm volatile("global_store_dwordx4 %0, %1, off sc0 sc1" :: "v"(p), "v"(v) : "memory");
}
// plain 16B store: lands in the writer XCD's L2 (write-through L1)
__device__ __forceinline__ void st4i_plain(float* p, i32x4 v){
  asm volatile("global_store_dwordx4 %0, %1, off" :: "v"(p), "v"(v) : "memory");
}
// 3-packet read, LLC path (sc0 sc1)
__device__ __forceinline__ void ld_pkt3(const float* p, i32x4 &a, i32x4 &b, i32x4 &c){
  asm volatile("global_load_dwordx4 %0, %3, off sc0 sc1\n\t"
               "global_load_dwordx4 %1, %3, off offset:16 sc0 sc1\n\t"
               "global_load_dwordx4 %2, %3, off offset:32 sc0 sc1\n\t"
               "s_waitcnt vmcnt(0)"
               : "=v"(a), "=v"(b), "=v"(c) : "v"(p) : "memory");
}
// 3-packet read, XCD-local path (sc0: bypass L1, hit local L2)
__device__ __forceinline__ void ld_pkt3_l2(const float* p, i32x4 &a, i32x4 &b, i32x4 &c){
  asm volatile("global_load_dwordx4 %0, %3, off sc0\n\t"
               "global_load_dwordx4 %1, %3, off offset:16 sc0\n\t"
               "global_load_dwordx4 %2, %3, off offset:32 sc0\n\t"
               "s_waitcnt vmcnt(0)"
               : "=v"(a), "=v"(b), "=v"(c) : "v"(p) : "memory");
}

__device__ __forceinline__ float4 load4g(const void* base, size_t off, int isb){
  if (isb){
    uint2 u = *(const uint2*)((const unsigned short*)base + off);
    return make_float4(bflo(u.x), bfhi(u.x), bflo(u.y), bfhi(u.y));
  }
  return *(const float4*)((const float*)base + off);
}
__device__ __forceinline__ float load1g(const void* base, int i, int isb){
  if (isb) return __uint_as_float(((unsigned int)((const unsigned short*)base)[i]) << 16);
  return ((const float*)base)[i];
}

// ---------- dtype detector ----------
__global__ void detect_dtype(const unsigned int* __restrict__ w, int* __restrict__ dflag){
  int tid = threadIdx.x;
  int wild = 0;
  for (int i = tid; i < 4096; i += 256){
    unsigned int lo = w[i] & 0xFFFFu;
    int e = (lo >> 7) & 0xFF;
    if (e < 0x60 || e > 0x9A) wild++;
  }
  __shared__ int cnt;
  if (tid == 0) cnt = 0;
  __syncthreads();
  atomicAdd(&cnt, wild);
  __syncthreads();
  if (tid == 0) *dflag = (cnt * 2 < 4096) ? 1 : 0;
}

// ---------- per-token embedding max-norm scale ----------
__global__ void embed_scale(const int* __restrict__ tok, const void* __restrict__ E,
                            const int* __restrict__ dflag, float* __restrict__ scale){
  int isb = *dflag;
  int t = blockIdx.x * 4 + (threadIdx.x >> 6);
  int lane = threadIdx.x & 63;
  if (t >= LSEQ) return;
  int token = tok[t];
  float ss = 0.f;
#pragma unroll
  for (int j = 0; j < 2; ++j){
    float4 v = load4g(E, (size_t)token * 512 + 4 * lane + 256 * j, isb);
    ss += v.x * v.x + v.y * v.y + v.z * v.z + v.w * v.w;
  }
  ss = wred(ss);
  if (lane == 0){
    float nrm = sqrtf(ss);
    scale[t] = fminf(1.0f, 1.0f / fmaxf(nrm, 1e-7f));
  }
}

// ---------- persistent pipelined 2-layer GRU, XCD-hierarchical broadcast ----
// 256 WGs x 512 thr. Waves 0-3: layer0 rows 4b..4b+3; waves 4-7: layer1 rows.
// Producers publish 3 self-tagged 16B packets/WG to the LLC arena (sc1).
// Per XCD, one relay WG (atomicCAS-elected via HW_REG_XCC_ID) polls the LLC
// arena and forwards packets via plain stores into an XCD-local arena (its
// own L2). Consumers poll the local arena with sc0 loads (L2-coherent within
// the XCD); bounded-spin sc1 fallback to the LLC arena guards any placement
// surprise (perf bug, never a hang). Tags make slot reuse (s%3) safe.
__global__ __launch_bounds__(512, 2) void gru_persistent(
    const int* __restrict__ tok, const void* __restrict__ E,
    const void* __restrict__ Wih0, const void* __restrict__ Whh0,
    const void* __restrict__ bih0, const void* __restrict__ bhh0,
    const void* __restrict__ Wih1, const void* __restrict__ Whh1,
    const void* __restrict__ bih1, const void* __restrict__ bhh1,
    float* __restrict__ wsf, void* __restrict__ outv)
{
  __shared__ float hb[2048];   // staged h0 (0..1023) | h1 (1024..2047)
  __shared__ float out8[8];    // this WG's 8 new h values
  __shared__ int sh_xcc, sh_isRelay;
  float* llcA = wsf + LLC_OFF;
  const int isb = ((const int*)wsf)[DTYPE_OFF];
  const float* scale = wsf + SCALE_OFF;

  const int tid = threadIdx.x, bid = blockIdx.x;
  const int wave = tid >> 6, lane = tid & 63;
  const bool isL0 = wave < 4;
  const int hidx = bid * 4 + (wave & 3);

  // ---- relay election: one WG per XCD ----
  if (tid == 0){
    // GETREG imm: id=20 (HW_REG_XCC_ID), offset=0, width=4 -> (3<<11)|20
    int x = __builtin_amdgcn_s_getreg((3 << 11) | 20) & 7;
    sh_xcc = x;
    int old = atomicCAS((int*)(wsf + CLAIM_OFF) + x, 0, bid + 1);
    sh_isRelay = (old == 0);
  }

  // ---- one-time weight load into registers, pinned ----
  float4 WA[3][4], WB[3][4];
  float bIr[3], bRr[3];
#pragma unroll
  for (int g = 0; g < 3; ++g){
    size_t row = (size_t)(g * 1024 + hidx);
    if (isL0){
#pragma unroll
      for (int j = 0; j < 4; ++j) WA[g][j] = load4g(Whh0, row * 1024 + 4 * lane + 256 * j, isb);
#pragma unroll
      for (int j = 0; j < 2; ++j) WB[g][j] = load4g(Wih0, row * 512 + 4 * lane + 256 * j, isb);
      WB[g][2] = make_float4(0, 0, 0, 0); WB[g][3] = make_float4(0, 0, 0, 0);
      bIr[g] = load1g(bih0, g * 1024 + hidx, isb);
      bRr[g] = load1g(bhh0, g * 1024 + hidx, isb);
    } else {
#pragma unroll
      for (int j = 0; j < 4; ++j) WA[g][j] = load4g(Wih1, row * 1024 + 4 * lane + 256 * j, isb);
#pragma unroll
      for (int j = 0; j < 4; ++j) WB[g][j] = load4g(Whh1, row * 1024 + 4 * lane + 256 * j, isb);
      bIr[g] = load1g(bih1, g * 1024 + hidx, isb);
      bRr[g] = load1g(bhh1, g * 1024 + hidx, isb);
    }
  }
#pragma unroll
  for (int g = 0; g < 3; ++g)
#pragma unroll
    for (int j = 0; j < 4; ++j){ keep4(WA[g][j]); keep4(WB[g][j]); }

  __syncthreads();
  const int   xcc     = sh_xcc;
  const bool  isRelay = (sh_isRelay != 0);
  float* locA = wsf + LOC_OFF + xcc * 12288;

  // ---- prologue prefetch: token 0 ----
  float4 xpre0 = make_float4(0,0,0,0), xpre1 = make_float4(0,0,0,0);
  float sc_next = 1.0f;
  if (isL0){
    int t0 = tok[0];
    sc_next = scale[0];
    xpre0 = load4g(E, (size_t)t0 * 512 + 4 * lane, isb);
    xpre1 = load4g(E, (size_t)t0 * 512 + 4 * lane + 256, isb);
  }

  for (int s = 0; s <= LSEQ; ++s){
    // ---- stage: obtain all 256 WGs' packets with tag==s, unpack to LDS ----
    if (tid < 256){
      const int slotOff = ((s + 2) % 3) * 4096 + tid * 16;
      const float* pkG = llcA + slotOff;
      i32x4 a, b, c;
      if (isRelay){
        for (;;){
          ld_pkt3(pkG, a, b, c);
          if (a.w == s && b.w == s && c.w == s) break;
          __builtin_amdgcn_s_sleep(1);
        }
        float* pkL = locA + slotOff;
        st4i_plain(pkL,     a);
        st4i_plain(pkL + 4, b);
        st4i_plain(pkL + 8, c);   // forward into local L2
      } else {
        const float* pkL = locA + slotOff;
        int spins = 0;
        for (;;){
          ld_pkt3_l2(pkL, a, b, c);
          if (a.w == s && b.w == s && c.w == s) break;
          if (++spins >= 256){          // safety net: go straight to LLC
            ld_pkt3(pkG, a, b, c);
            if (a.w == s && b.w == s && c.w == s) break;
            spins = 0;
          }
          __builtin_amdgcn_s_sleep(1);
        }
      }
      hb[4*tid+0] = __int_as_float(a.x); hb[4*tid+1] = __int_as_float(a.y);
      hb[4*tid+2] = __int_as_float(a.z); hb[4*tid+3] = __int_as_float(b.x);
      hb[1024+4*tid+0] = __int_as_float(b.y); hb[1024+4*tid+1] = __int_as_float(b.z);
      hb[1024+4*tid+2] = __int_as_float(c.x); hb[1024+4*tid+3] = __int_as_float(c.y);
    }
    __syncthreads();

    const bool active = isL0 ? (s < LSEQ) : (s >= 1);
    float hprev = isL0 ? hb[hidx] : hb[1024 + hidx];
    float hnew = hprev;
    if (active){
      float4 xr[4];
      float sc = 1.0f;
      if (isL0){
        sc = sc_next;
        xr[0] = xpre0; xr[1] = xpre1;
        xr[2] = make_float4(0,0,0,0); xr[3] = make_float4(0,0,0,0);
      } else {
#pragma unroll
        for (int j = 0; j < 4; ++j) xr[j] = ((const float4*)(hb + 1024))[lane + 64 * j];
      }
      float4 h0r[4];
#pragma unroll
      for (int j = 0; j < 4; ++j) h0r[j] = ((const float4*)hb)[lane + 64 * j];

      float a1r = 0, a1z = 0, a1n = 0, a2r = 0, a2z = 0, a2n = 0;
#pragma unroll
      for (int j = 0; j < 4; ++j){
        float4 h = h0r[j], x = xr[j], w;
        w = WA[0][j]; a1r = fmaf(w.w, h.w, fmaf(w.z, h.z, fmaf(w.y, h.y, fmaf(w.x, h.x, a1r))));
        w = WA[1][j]; a1z = fmaf(w.w, h.w, fmaf(w.z, h.z, fmaf(w.y, h.y, fmaf(w.x, h.x, a1z))));
        w = WA[2][j]; a1n = fmaf(w.w, h.w, fmaf(w.z, h.z, fmaf(w.y, h.y, fmaf(w.x, h.x, a1n))));
        w = WB[0][j]; a2r = fmaf(w.w, x.w, fmaf(w.z, x.z, fmaf(w.y, x.y, fmaf(w.x, x.x, a2r))));
        w = WB[1][j]; a2z = fmaf(w.w, x.w, fmaf(w.z, x.z, fmaf(w.y, x.y, fmaf(w.x, x.x, a2z))));
        w = WB[2][j]; a2n = fmaf(w.w, x.w, fmaf(w.z, x.z, fmaf(w.y, x.y, fmaf(w.x, x.x, a2n))));
      }
      a1r = wred(a1r); a1z = wred(a1z); a1n = wred(a1n);
      a2r = wred(a2r); a2z = wred(a2z); a2n = wred(a2n);

      float ipr, ipz, ipn, rpr, rpz, rpn;
      if (isL0){ ipr = sc * a2r + bIr[0]; ipz = sc * a2z + bIr[1]; ipn = sc * a2n + bIr[2];
                 rpr = a1r + bRr[0];      rpz = a1z + bRr[1];      rpn = a1n + bRr[2]; }
      else     { ipr = a1r + bIr[0];      ipz = a1z + bIr[1];      ipn = a1n + bIr[2];
                 rpr = a2r + bRr[0];      rpz = a2z + bRr[1];      rpn = a2n + bRr[2]; }

      float r = 1.0f / (1.0f + expf(-(ipr + rpr)));
      float z = 1.0f / (1.0f + expf(-(ipz + rpz)));
      float n = tanhf(ipn + r * rpn);
      hnew = (1.0f - z) * n + z * hprev;

      if (lane == 0){
        if (isb){
          __hip_bfloat16* ob = (__hip_bfloat16*)outv;
          if (isL0 && s == LSEQ - 1) ob[1024 + hidx] = __float2bfloat16(hnew);       // hidden[0]
          if (!isL0 && s == LSEQ)  { ob[hidx] = __float2bfloat16(hnew);              // out
                                     ob[2048 + hidx] = __float2bfloat16(hnew); }     // hidden[1]
        } else {
          float* of = (float*)outv;
          if (isL0 && s == LSEQ - 1) of[1024 + hidx] = hnew;
          if (!isL0 && s == LSEQ)  { of[hidx] = hnew; of[2048 + hidx] = hnew; }
        }
      }
    }
    if (lane == 0) out8[wave] = hnew;   // inactive waves republish hprev

    if (s < LSEQ){
      __syncthreads();   // out8 complete
      if (tid == 0){
        float tagf = __int_as_float(s + 1);
        f32x4 P0 = { out8[0], out8[1], out8[2], tagf };
        f32x4 P1 = { out8[3], out8[4], out8[5], tagf };
        f32x4 P2 = { out8[6], out8[7], 0.0f,    tagf };
        float* pk = llcA + (s % 3) * 4096 + bid * 16;
        st4_sc(pk,     P0);
        st4_sc(pk + 4, P1);
        st4_sc(pk + 8, P2);   // fire-and-forget: tag travels with data
      }
      // prefetch next token's x-row (normal cached loads; consumed next iter)
      if (isL0 && s + 1 < LSEQ){
        int t1 = tok[s + 1];
        sc_next = scale[s + 1];
        xpre0 = load4g(E, (size_t)t1 * 512 + 4 * lane, isb);
        xpre1 = load4g(E, (size_t)t1 * 512 + 4 * lane + 256, isb);
      }
    }
  }
}

extern "C" void kernel_launch(void* const* d_in, const int* in_sizes, int n_in,
                              void* d_out, int out_size, void* d_ws, size_t ws_size,
                              hipStream_t stream) {
  const int*  tokens = (const int*)d_in[0];
  const void* E    = d_in[1];
  const void* Wih0 = d_in[2];
  const void* Whh0 = d_in[3];
  const void* bih0 = d_in[4];
  const void* bhh0 = d_in[5];
  const void* Wih1 = d_in[6];
  const void* Whh1 = d_in[7];
  const void* bih1 = d_in[8];
  const void* bhh1 = d_in[9];
  float* wsf = (float*)d_ws;

  // zero: LLC arena + 8 local arenas + relay claims + dtype flag
  (void)hipMemsetAsync(d_ws, 0, SCALE_OFF * 4, stream);
  hipLaunchKernelGGL(detect_dtype, dim3(1), dim3(256), 0, stream,
                     (const unsigned int*)E, ((int*)d_ws) + DTYPE_OFF);
  hipLaunchKernelGGL(embed_scale, dim3(1024), dim3(256), 0, stream,
                     tokens, E, ((const int*)d_ws) + DTYPE_OFF, wsf + SCALE_OFF);

  void* args[] = { (void*)&tokens, (void*)&E, (void*)&Wih0, (void*)&Whh0,
                   (void*)&bih0, (void*)&bhh0, (void*)&Wih1, (void*)&Whh1,
                   (void*)&bih1, (void*)&bhh1, (void*)&wsf, (void*)&d_out };
  (void)hipLaunchCooperativeKernel((void*)gru_persistent, dim3(256), dim3(512),
                                   args, 0, stream);
}

// Round 8
// 16280.473 us; speedup vs baseline: 11.7251x; 11.7251x over previous
//
#include <hip/hip_runtime.h>
#include <hip/hip_bf16.h>
#include <stdint.h>

#define LSEQ 4096

// workspace float offsets
#define LLC_OFF   0        // 3 slots x 4096 floats (256 WGs x 16)      = 12288 f
#define LOC_OFF   12288    // 8 XCDs x 3 slots x 4096 floats            = 98304 f
#define CLAIM_OFF 110592   // 8 ints (relay election)
#define DTYPE_OFF 110600   // 1 int
#define SCALE_OFF 110656   // 4096 f

typedef float f32x4 __attribute__((ext_vector_type(4)));
typedef int   i32x4 __attribute__((ext_vector_type(4)));

// ---------- helpers ----------
__device__ __forceinline__ float bflo(unsigned int u){ return __uint_as_float(u << 16); }
__device__ __forceinline__ float bfhi(unsigned int u){ return __uint_as_float(u & 0xFFFF0000u); }

__device__ __forceinline__ float wred(float v){
#pragma unroll
  for (int m = 1; m < 64; m <<= 1) v += __shfl_xor(v, m, 64);
  return v;
}

__device__ __forceinline__ void keep4(float4 &v){
  asm volatile("" : "+v"(v.x), "+v"(v.y), "+v"(v.z), "+v"(v.w));
}

// sc0 sc1: LLC-coherent (bypass caches to coherence point)
__device__ __forceinline__ void st4_sc(float* p, f32x4 v){
  asm volatile("global_store_dwordx4 %0, %1, off sc0 sc1" :: "v"(p), "v"(v) : "memory");
}
// plain 16B store: write-back into the storing XCD's L2
__device__ __forceinline__ void st4i_plain(float* p, i32x4 v){
  asm volatile("global_store_dwordx4 %0, %1, off" :: "v"(p), "v"(v) : "memory");
}
// 3-packet read, LLC path (sc0 sc1) — always-correct fallback/relay path
__device__ __forceinline__ void ld_pkt3(const float* p, i32x4 &a, i32x4 &b, i32x4 &c){
  asm volatile("global_load_dwordx4 %0, %3, off sc0 sc1\n\t"
               "global_load_dwordx4 %1, %3, off offset:16 sc0 sc1\n\t"
               "global_load_dwordx4 %2, %3, off offset:32 sc0 sc1\n\t"
               "s_waitcnt vmcnt(0)"
               : "=v"(a), "=v"(b), "=v"(c) : "v"(p) : "memory");
}
// 3-packet read, XCD-local path: non-temporal loads — no L1 allocation (so no
// stale L1 hits possible: these addresses are ONLY ever nt-loaded), serviced
// from the XCD L2 where the relay's plain stores land.
__device__ __forceinline__ void ld_pkt3_nt(const float* p, i32x4 &a, i32x4 &b, i32x4 &c){
  const i32x4* q = (const i32x4*)p;
  a = __builtin_nontemporal_load(q);
  b = __builtin_nontemporal_load(q + 1);
  c = __builtin_nontemporal_load(q + 2);
  asm volatile("" ::: "memory");   // no CSE across retry iterations
}

__device__ __forceinline__ float4 load4g(const void* base, size_t off, int isb){
  if (isb){
    uint2 u = *(const uint2*)((const unsigned short*)base + off);
    return make_float4(bflo(u.x), bfhi(u.x), bflo(u.y), bfhi(u.y));
  }
  return *(const float4*)((const float*)base + off);
}
__device__ __forceinline__ float load1g(const void* base, int i, int isb){
  if (isb) return __uint_as_float(((unsigned int)((const unsigned short*)base)[i]) << 16);
  return ((const float*)base)[i];
}

// ---------- dtype detector ----------
__global__ void detect_dtype(const unsigned int* __restrict__ w, int* __restrict__ dflag){
  int tid = threadIdx.x;
  int wild = 0;
  for (int i = tid; i < 4096; i += 256){
    unsigned int lo = w[i] & 0xFFFFu;
    int e = (lo >> 7) & 0xFF;
    if (e < 0x60 || e > 0x9A) wild++;
  }
  __shared__ int cnt;
  if (tid == 0) cnt = 0;
  __syncthreads();
  atomicAdd(&cnt, wild);
  __syncthreads();
  if (tid == 0) *dflag = (cnt * 2 < 4096) ? 1 : 0;
}

// ---------- per-token embedding max-norm scale ----------
__global__ void embed_scale(const int* __restrict__ tok, const void* __restrict__ E,
                            const int* __restrict__ dflag, float* __restrict__ scale){
  int isb = *dflag;
  int t = blockIdx.x * 4 + (threadIdx.x >> 6);
  int lane = threadIdx.x & 63;
  if (t >= LSEQ) return;
  int token = tok[t];
  float ss = 0.f;
#pragma unroll
  for (int j = 0; j < 2; ++j){
    float4 v = load4g(E, (size_t)token * 512 + 4 * lane + 256 * j, isb);
    ss += v.x * v.x + v.y * v.y + v.z * v.z + v.w * v.w;
  }
  ss = wred(ss);
  if (lane == 0){
    float nrm = sqrtf(ss);
    scale[t] = fminf(1.0f, 1.0f / fmaxf(nrm, 1e-7f));
  }
}

// ---------- persistent pipelined 2-layer GRU, XCD-hierarchical broadcast ----
// Producers -> LLC arena (sc1, self-tagged packets, slot s%3).
// Relay WG per XCD (CAS-elected on HW_REG_XCC_ID): polls LLC arena, forwards
// packets via plain stores into an XCD-local arena (lives in its L2).
// Consumers: nt-load poll of the local arena (L2 hit, no L1 staleness);
// after 6 misses switch to the LLC arena until success (bounded degradation,
// never a hang, never a 256-spin storm).
__global__ __launch_bounds__(512, 2) void gru_persistent(
    const int* __restrict__ tok, const void* __restrict__ E,
    const void* __restrict__ Wih0, const void* __restrict__ Whh0,
    const void* __restrict__ bih0, const void* __restrict__ bhh0,
    const void* __restrict__ Wih1, const void* __restrict__ Whh1,
    const void* __restrict__ bih1, const void* __restrict__ bhh1,
    float* __restrict__ wsf, void* __restrict__ outv)
{
  __shared__ float hb[2048];   // staged h0 (0..1023) | h1 (1024..2047)
  __shared__ float out8[8];    // this WG's 8 new h values
  __shared__ int sh_xcc, sh_isRelay;
  float* llcA = wsf + LLC_OFF;
  const int isb = ((const int*)wsf)[DTYPE_OFF];
  const float* scale = wsf + SCALE_OFF;

  const int tid = threadIdx.x, bid = blockIdx.x;
  const int wave = tid >> 6, lane = tid & 63;
  const bool isL0 = wave < 4;
  const int hidx = bid * 4 + (wave & 3);

  // ---- relay election: one WG per XCD ----
  if (tid == 0){
    int x = __builtin_amdgcn_s_getreg((3 << 11) | 20) & 7;  // HW_REG_XCC_ID
    sh_xcc = x;
    int old = atomicCAS((int*)(wsf + CLAIM_OFF) + x, 0, bid + 1);
    sh_isRelay = (old == 0);
  }

  // ---- one-time weight load into registers, pinned ----
  float4 WA[3][4], WB[3][4];
  float bIr[3], bRr[3];
#pragma unroll
  for (int g = 0; g < 3; ++g){
    size_t row = (size_t)(g * 1024 + hidx);
    if (isL0){
#pragma unroll
      for (int j = 0; j < 4; ++j) WA[g][j] = load4g(Whh0, row * 1024 + 4 * lane + 256 * j, isb);
#pragma unroll
      for (int j = 0; j < 2; ++j) WB[g][j] = load4g(Wih0, row * 512 + 4 * lane + 256 * j, isb);
      WB[g][2] = make_float4(0, 0, 0, 0); WB[g][3] = make_float4(0, 0, 0, 0);
      bIr[g] = load1g(bih0, g * 1024 + hidx, isb);
      bRr[g] = load1g(bhh0, g * 1024 + hidx, isb);
    } else {
#pragma unroll
      for (int j = 0; j < 4; ++j) WA[g][j] = load4g(Wih1, row * 1024 + 4 * lane + 256 * j, isb);
#pragma unroll
      for (int j = 0; j < 4; ++j) WB[g][j] = load4g(Whh1, row * 1024 + 4 * lane + 256 * j, isb);
      bIr[g] = load1g(bih1, g * 1024 + hidx, isb);
      bRr[g] = load1g(bhh1, g * 1024 + hidx, isb);
    }
  }
#pragma unroll
  for (int g = 0; g < 3; ++g)
#pragma unroll
    for (int j = 0; j < 4; ++j){ keep4(WA[g][j]); keep4(WB[g][j]); }

  __syncthreads();
  const int   xcc     = sh_xcc;
  const bool  isRelay = (sh_isRelay != 0);
  float* locA = wsf + LOC_OFF + xcc * 12288;

  // ---- prologue prefetch: token 0 ----
  float4 xpre0 = make_float4(0,0,0,0), xpre1 = make_float4(0,0,0,0);
  float sc_next = 1.0f;
  if (isL0){
    int t0 = tok[0];
    sc_next = scale[0];
    xpre0 = load4g(E, (size_t)t0 * 512 + 4 * lane, isb);
    xpre1 = load4g(E, (size_t)t0 * 512 + 4 * lane + 256, isb);
  }

  for (int s = 0; s <= LSEQ; ++s){
    // ---- stage: obtain all 256 WGs' packets with tag==s, unpack to LDS ----
    if (tid < 256){
      const int slotOff = ((s + 2) % 3) * 4096 + tid * 16;
      const float* pkG = llcA + slotOff;
      i32x4 a, b, c;
      if (isRelay){
        for (;;){
          ld_pkt3(pkG, a, b, c);
          if (a.w == s && b.w == s && c.w == s) break;
          __builtin_amdgcn_s_sleep(1);
        }
        float* pkL = locA + slotOff;
        st4i_plain(pkL,     a);
        st4i_plain(pkL + 4, b);
        st4i_plain(pkL + 8, c);   // forward into this XCD's L2
      } else {
        const float* pkL = locA + slotOff;
        bool got = false;
        for (int r = 0; r < 6; ++r){          // phase 1: XCD-local L2 poll
          ld_pkt3_nt(pkL, a, b, c);
          if (a.w == s && b.w == s && c.w == s){ got = true; break; }
          __builtin_amdgcn_s_sleep(1);
        }
        while (!got){                          // phase 2: sticky LLC poll
          ld_pkt3(pkG, a, b, c);
          if (a.w == s && b.w == s && c.w == s) got = true;
          else __builtin_amdgcn_s_sleep(1);
        }
      }
      hb[4*tid+0] = __int_as_float(a.x); hb[4*tid+1] = __int_as_float(a.y);
      hb[4*tid+2] = __int_as_float(a.z); hb[4*tid+3] = __int_as_float(b.x);
      hb[1024+4*tid+0] = __int_as_float(b.y); hb[1024+4*tid+1] = __int_as_float(b.z);
      hb[1024+4*tid+2] = __int_as_float(c.x); hb[1024+4*tid+3] = __int_as_float(c.y);
    }
    __syncthreads();

    const bool active = isL0 ? (s < LSEQ) : (s >= 1);
    float hprev = isL0 ? hb[hidx] : hb[1024 + hidx];
    float hnew = hprev;
    if (active){
      float4 xr[4];
      float sc = 1.0f;
      if (isL0){
        sc = sc_next;
        xr[0] = xpre0; xr[1] = xpre1;
        xr[2] = make_float4(0,0,0,0); xr[3] = make_float4(0,0,0,0);
      } else {
#pragma unroll
        for (int j = 0; j < 4; ++j) xr[j] = ((const float4*)(hb + 1024))[lane + 64 * j];
      }
      float4 h0r[4];
#pragma unroll
      for (int j = 0; j < 4; ++j) h0r[j] = ((const float4*)hb)[lane + 64 * j];

      float a1r = 0, a1z = 0, a1n = 0, a2r = 0, a2z = 0, a2n = 0;
#pragma unroll
      for (int j = 0; j < 4; ++j){
        float4 h = h0r[j], x = xr[j], w;
        w = WA[0][j]; a1r = fmaf(w.w, h.w, fmaf(w.z, h.z, fmaf(w.y, h.y, fmaf(w.x, h.x, a1r))));
        w = WA[1][j]; a1z = fmaf(w.w, h.w, fmaf(w.z, h.z, fmaf(w.y, h.y, fmaf(w.x, h.x, a1z))));
        w = WA[2][j]; a1n = fmaf(w.w, h.w, fmaf(w.z, h.z, fmaf(w.y, h.y, fmaf(w.x, h.x, a1n))));
        w = WB[0][j]; a2r = fmaf(w.w, x.w, fmaf(w.z, x.z, fmaf(w.y, x.y, fmaf(w.x, x.x, a2r))));
        w = WB[1][j]; a2z = fmaf(w.w, x.w, fmaf(w.z, x.z, fmaf(w.y, x.y, fmaf(w.x, x.x, a2z))));
        w = WB[2][j]; a2n = fmaf(w.w, x.w, fmaf(w.z, x.z, fmaf(w.y, x.y, fmaf(w.x, x.x, a2n))));
      }
      a1r = wred(a1r); a1z = wred(a1z); a1n = wred(a1n);
      a2r = wred(a2r); a2z = wred(a2z); a2n = wred(a2n);

      float ipr, ipz, ipn, rpr, rpz, rpn;
      if (isL0){ ipr = sc * a2r + bIr[0]; ipz = sc * a2z + bIr[1]; ipn = sc * a2n + bIr[2];
                 rpr = a1r + bRr[0];      rpz = a1z + bRr[1];      rpn = a1n + bRr[2]; }
      else     { ipr = a1r + bIr[0];      ipz = a1z + bIr[1];      ipn = a1n + bIr[2];
                 rpr = a2r + bRr[0];      rpz = a2z + bRr[1];      rpn = a2n + bRr[2]; }

      float r = 1.0f / (1.0f + expf(-(ipr + rpr)));
      float z = 1.0f / (1.0f + expf(-(ipz + rpz)));
      float n = tanhf(ipn + r * rpn);
      hnew = (1.0f - z) * n + z * hprev;

      if (lane == 0){
        if (isb){
          __hip_bfloat16* ob = (__hip_bfloat16*)outv;
          if (isL0 && s == LSEQ - 1) ob[1024 + hidx] = __float2bfloat16(hnew);       // hidden[0]
          if (!isL0 && s == LSEQ)  { ob[hidx] = __float2bfloat16(hnew);              // out
                                     ob[2048 + hidx] = __float2bfloat16(hnew); }     // hidden[1]
        } else {
          float* of = (float*)outv;
          if (isL0 && s == LSEQ - 1) of[1024 + hidx] = hnew;
          if (!isL0 && s == LSEQ)  { of[hidx] = hnew; of[2048 + hidx] = hnew; }
        }
      }
    }
    if (lane == 0) out8[wave] = hnew;   // inactive waves republish hprev

    if (s < LSEQ){
      __syncthreads();   // out8 complete
      if (tid == 0){
        float tagf = __int_as_float(s + 1);
        f32x4 P0 = { out8[0], out8[1], out8[2], tagf };
        f32x4 P1 = { out8[3], out8[4], out8[5], tagf };
        f32x4 P2 = { out8[6], out8[7], 0.0f,    tagf };
        float* pk = llcA + (s % 3) * 4096 + bid * 16;
        st4_sc(pk,     P0);
        st4_sc(pk + 4, P1);
        st4_sc(pk + 8, P2);   // fire-and-forget: tag travels with data
      }
      // prefetch next token's x-row (normal cached loads; consumed next iter)
      if (isL0 && s + 1 < LSEQ){
        int t1 = tok[s + 1];
        sc_next = scale[s + 1];
        xpre0 = load4g(E, (size_t)t1 * 512 + 4 * lane, isb);
        xpre1 = load4g(E, (size_t)t1 * 512 + 4 * lane + 256, isb);
      }
    }
  }
}

extern "C" void kernel_launch(void* const* d_in, const int* in_sizes, int n_in,
                              void* d_out, int out_size, void* d_ws, size_t ws_size,
                              hipStream_t stream) {
  const int*  tokens = (const int*)d_in[0];
  const void* E    = d_in[1];
  const void* Wih0 = d_in[2];
  const void* Whh0 = d_in[3];
  const void* bih0 = d_in[4];
  const void* bhh0 = d_in[5];
  const void* Wih1 = d_in[6];
  const void* Whh1 = d_in[7];
  const void* bih1 = d_in[8];
  const void* bhh1 = d_in[9];
  float* wsf = (float*)d_ws;

  // zero: LLC arena + 8 local arenas + relay claims + dtype flag
  (void)hipMemsetAsync(d_ws, 0, SCALE_OFF * 4, stream);
  hipLaunchKernelGGL(detect_dtype, dim3(1), dim3(256), 0, stream,
                     (const unsigned int*)E, ((int*)d_ws) + DTYPE_OFF);
  hipLaunchKernelGGL(embed_scale, dim3(1024), dim3(256), 0, stream,
                     tokens, E, ((const int*)d_ws) + DTYPE_OFF, wsf + SCALE_OFF);

  void* args[] = { (void*)&tokens, (void*)&E, (void*)&Wih0, (void*)&Whh0,
                   (void*)&bih0, (void*)&bhh0, (void*)&Wih1, (void*)&Whh1,
                   (void*)&bih1, (void*)&bhh1, (void*)&wsf, (void*)&d_out };
  (void)hipLaunchCooperativeKernel((void*)gru_persistent, dim3(256), dim3(512),
                                   args, 0, stream);
}